// Round 4
// baseline (56.983 us; speedup 1.0000x reference)
//
#include <hip/hip_runtime.h>
#include <hip/hip_bf16.h>
#include <float.h>

// ChamferLoss: preds [B,N,3] f32, gts [B,N,3] f32 -> scalar f32
// R4: pack 2 targets per instruction via v_pk_fma_f32 (VOP3P packed fp32,
// full-rate on CDNA2+ -- FP32 spec peak = 2x FP64 peak comes from this).
// Inner loop: per 2 target-pairs x Q=4 queries, 4 broadcast ds_read_b128
// (SoA pair layout) + per query 6 pk_fma + 2 min3 = 2.0 VALU instr/pair.

#define BLK  256
#define SEG  16
#define Q    4

typedef float f32x2 __attribute__((ext_vector_type(2)));
typedef float f32x4 __attribute__((ext_vector_type(4)));

__device__ __forceinline__ unsigned int enc_f32(float f) {
    unsigned int u = __float_as_uint(f);
    return (u & 0x80000000u) ? ~u : (u | 0x80000000u);
}
__device__ __forceinline__ float dec_f32(unsigned int k) {
    return __uint_as_float((k & 0x80000000u) ? (k & 0x7FFFFFFFu) : ~k);
}
__device__ __forceinline__ float min3f(float a, float b, float c) {
    float r;
    asm("v_min3_f32 %0, %1, %2, %3" : "=v"(r) : "v"(a), "v"(b), "v"(c));
    return r;
}
__device__ __forceinline__ f32x2 pk_fma(f32x2 a, f32x2 b, f32x2 c) {
    f32x2 d;
    asm("v_pk_fma_f32 %0, %1, %2, %3" : "=v"(d) : "v"(a), "v"(b), "v"(c));
    return d;
}

__global__ __launch_bounds__(BLK) void chamfer_min_kernel(
    const float* __restrict__ preds, const float* __restrict__ gts,
    unsigned int* __restrict__ keys, int N) {

    const int seg = blockIdx.z % SEG;
    const int dir = blockIdx.z / SEG;     // 0: query=preds ; 1: query=gts
    const int b   = blockIdx.y;
    const int tid = threadIdx.x;
    const int TT  = N / SEG;              // 512 targets per segment

    const float* Aq = dir == 0 ? preds : gts;
    const float* Bt = dir == 0 ? gts   : preds;
    const float* Ab = Aq + (size_t)b * N * 3;
    const float* Bb = Bt + (size_t)b * N * 3;

    // SoA pair layout: element p holds coords of targets (2p, 2p+1)
    __shared__ f32x2 shx[256], shy[256], shz[256], shw[256];   // TT <= 512

    // Q queries per thread, strided by BLK
    const int qbase = blockIdx.x * (BLK * Q);
    f32x2 a2x[Q], a2y[Q], a2z[Q];
    float an[Q];
    bool  vq[Q];
    #pragma unroll
    for (int q = 0; q < Q; ++q) {
        int idx = qbase + q * BLK + tid;
        vq[q] = idx < N;
        int ci = vq[q] ? idx : 0;
        float ax = Ab[ci * 3 + 0];
        float ay = Ab[ci * 3 + 1];
        float az = Ab[ci * 3 + 2];
        a2x[q] = f32x2{-2.f * ax, -2.f * ax};
        a2y[q] = f32x2{-2.f * ay, -2.f * ay};
        a2z[q] = f32x2{-2.f * az, -2.f * az};
        an[q]  = ax * ax + ay * ay + az * az;
    }

    // Stage: each thread stages one target pair (j0, j0+1); j0 even ->
    // three 8B-aligned float2 global loads.
    for (int p = tid; p < (TT >> 1); p += BLK) {
        int j0 = seg * TT + 2 * p;
        const f32x2* src = (const f32x2*)(Bb + (size_t)j0 * 3);
        f32x2 v01 = src[0];   // x0 y0
        f32x2 v23 = src[1];   // z0 x1
        f32x2 v45 = src[2];   // y1 z1
        shx[p] = f32x2{v01.x, v23.y};
        shy[p] = f32x2{v01.y, v45.x};
        shz[p] = f32x2{v23.x, v45.y};
        shw[p] = f32x2{v01.x * v01.x + v01.y * v01.y + v23.x * v23.x,
                       v23.y * v23.y + v45.x * v45.x + v45.y * v45.y};
    }
    __syncthreads();

    float m[Q];
    #pragma unroll
    for (int q = 0; q < Q; ++q) m[q] = FLT_MAX;

    const f32x4* X4 = (const f32x4*)shx;
    const f32x4* Y4 = (const f32x4*)shy;
    const f32x4* Z4 = (const f32x4*)shz;
    const f32x4* W4 = (const f32x4*)shw;

    const int KITER = TT >> 2;            // 4 targets (2 pairs) per iter
    #pragma unroll 2
    for (int k = 0; k < KITER; ++k) {
        f32x4 X = X4[k], Y = Y4[k], Z = Z4[k], W = W4[k];
        #pragma unroll
        for (int q = 0; q < Q; ++q) {
            f32x2 d0 = pk_fma(a2x[q], X.lo, pk_fma(a2y[q], Y.lo, pk_fma(a2z[q], Z.lo, W.lo)));
            f32x2 d1 = pk_fma(a2x[q], X.hi, pk_fma(a2y[q], Y.hi, pk_fma(a2z[q], Z.hi, W.hi)));
            m[q] = min3f(d0.x, d0.y, m[q]);
            m[q] = min3f(d1.x, d1.y, m[q]);
        }
    }

    #pragma unroll
    for (int q = 0; q < Q; ++q) {
        if (vq[q]) {
            int idx = qbase + q * BLK + tid;
            unsigned int* slot = keys + ((size_t)(dir * 4 + b) * N + idx);
            atomicMin(slot, enc_f32(m[q] + an[q]));
        }
    }
}

__global__ __launch_bounds__(BLK) void chamfer_sum_kernel(
    const unsigned int* __restrict__ keys, float* __restrict__ out, int M) {

    __shared__ float psum[BLK / 64];
    int gid = blockIdx.x * BLK + threadIdx.x;
    int stride = gridDim.x * BLK;
    float s = 0.f;
    for (int i = gid; i < M; i += stride) s += dec_f32(keys[i]);
    for (int off = 32; off > 0; off >>= 1) s += __shfl_down(s, off, 64);
    if ((threadIdx.x & 63) == 0) psum[threadIdx.x >> 6] = s;
    __syncthreads();
    if (threadIdx.x == 0) {
        float t = 0.f;
        for (int w = 0; w < BLK / 64; ++w) t += psum[w];
        atomicAdd(out, t);
    }
}

// ---- Fallback (single-kernel) if ws too small / odd shapes ----
__global__ __launch_bounds__(BLK) void chamfer_kernel_fb(
    const float* __restrict__ preds, const float* __restrict__ gts,
    float* __restrict__ out, int N) {
    const int dir = blockIdx.z;
    const int b   = blockIdx.y;
    const int tid = threadIdx.x;
    const int idx = blockIdx.x * BLK + tid;
    const float* Aq = dir == 0 ? preds : gts;
    const float* Bt = dir == 0 ? gts   : preds;
    const float* Ab = Aq + (size_t)b * N * 3;
    const float* Bb = Bt + (size_t)b * N * 3;
    __shared__ float4 lds[2048];
    __shared__ float  psum[BLK / 64];
    float a2x = 0.f, a2y = 0.f, a2z = 0.f, an = 0.f;
    const bool valid = idx < N;
    if (valid) {
        float ax = Ab[idx * 3], ay = Ab[idx * 3 + 1], az = Ab[idx * 3 + 2];
        a2x = -2.f * ax; a2y = -2.f * ay; a2z = -2.f * az;
        an  = ax * ax + ay * ay + az * az;
    }
    float m0 = FLT_MAX, m1 = FLT_MAX, m2 = FLT_MAX, m3 = FLT_MAX;
    for (int t = 0; t < N; t += 2048) {
        int lim = min(2048, N - t);
        for (int k = tid; k < lim; k += BLK) {
            int j = t + k;
            float x = Bb[j * 3], y = Bb[j * 3 + 1], z = Bb[j * 3 + 2];
            lds[k] = make_float4(x, y, z, x * x + y * y + z * z);
        }
        __syncthreads();
        for (int k = 0; k + 3 < lim; k += 4) {
            float4 p0 = lds[k], p1 = lds[k + 1], p2 = lds[k + 2], p3 = lds[k + 3];
            m0 = fminf(m0, fmaf(a2x, p0.x, fmaf(a2y, p0.y, fmaf(a2z, p0.z, p0.w))));
            m1 = fminf(m1, fmaf(a2x, p1.x, fmaf(a2y, p1.y, fmaf(a2z, p1.z, p1.w))));
            m2 = fminf(m2, fmaf(a2x, p2.x, fmaf(a2y, p2.y, fmaf(a2z, p2.z, p2.w))));
            m3 = fminf(m3, fmaf(a2x, p3.x, fmaf(a2y, p3.y, fmaf(a2z, p3.z, p3.w))));
        }
        for (int k = lim & ~3; k < lim; ++k) {
            float4 p0 = lds[k];
            m0 = fminf(m0, fmaf(a2x, p0.x, fmaf(a2y, p0.y, fmaf(a2z, p0.z, p0.w))));
        }
        __syncthreads();
    }
    float m = fminf(fminf(m0, m1), fminf(m2, m3)) + an;
    float contrib = valid ? m : 0.f;
    for (int off = 32; off > 0; off >>= 1) contrib += __shfl_down(contrib, off, 64);
    if ((tid & 63) == 0) psum[tid >> 6] = contrib;
    __syncthreads();
    if (tid == 0) {
        float s = 0.f;
        for (int w = 0; w < BLK / 64; ++w) s += psum[w];
        atomicAdd(out, s);
    }
}

extern "C" void kernel_launch(void* const* d_in, const int* in_sizes, int n_in,
                              void* d_out, int out_size, void* d_ws, size_t ws_size,
                              hipStream_t stream) {
    const float* preds = (const float*)d_in[0];
    const float* gts   = (const float*)d_in[1];
    float* out = (float*)d_out;

    const int B = 4, D = 3;
    const int N = in_sizes[0] / (B * D);   // 8192

    hipMemsetAsync(out, 0, sizeof(float) * out_size, stream);

    const size_t keys_bytes = (size_t)2 * B * N * sizeof(unsigned int); // 256 KB
    const int TT = N / SEG;
    if (ws_size >= keys_bytes && (N % SEG) == 0 && TT <= 512 && (TT % 4) == 0) {
        unsigned int* keys = (unsigned int*)d_ws;
        hipMemsetAsync(keys, 0xFF, keys_bytes, stream);
        dim3 grid((N + BLK * Q - 1) / (BLK * Q), B, 2 * SEG);
        chamfer_min_kernel<<<grid, BLK, 0, stream>>>(preds, gts, keys, N);
        int M = 2 * B * N;
        chamfer_sum_kernel<<<64, BLK, 0, stream>>>(keys, out, M);
    } else {
        dim3 grid((N + BLK - 1) / BLK, B, 2);
        chamfer_kernel_fb<<<grid, BLK, 0, stream>>>(preds, gts, out, N);
    }
}